// Round 14
// baseline (113.179 us; speedup 1.0000x reference)
//
#include <hip/hip_runtime.h>
#include <hip/hip_bf16.h>
#include <stdint.h>

typedef __attribute__((ext_vector_type(8)))  __bf16 bf16x8;
typedef __attribute__((ext_vector_type(8)))  short  short8;
typedef __attribute__((ext_vector_type(4)))  float  f32x4;
typedef __attribute__((ext_vector_type(16))) float  f32x16;

#define MFMA16(a, b, c) __builtin_amdgcn_mfma_f32_16x16x32_bf16((a), (b), (c), 0, 0, 0)
#define MFMA32(a, b, c) __builtin_amdgcn_mfma_f32_32x32x16_bf16((a), (b), (c), 0, 0, 0)

__device__ __forceinline__ unsigned short f32_bf16(float f) {
  union { float f; unsigned u; } v; v.f = f;
  unsigned r = v.u + 0x7FFFu + ((v.u >> 16) & 1u);
  return (unsigned short)(r >> 16);
}

// bare v_exp_f32 (2^x): OCML exp2f carries denormal guards (~5 insts)
__device__ __forceinline__ float fast_exp2(float x) {
#if __has_builtin(__builtin_amdgcn_exp2f)
  return __builtin_amdgcn_exp2f(x);
#else
  return __expf(x * 0.69314718f);
#endif
}

// async global->LDS, 16B per lane; LDS dest is wave-uniform base (+lane*16 by HW)
__device__ __forceinline__ void gload16(const unsigned short* g, unsigned short* l) {
  __builtin_amdgcn_global_load_lds(
      (const __attribute__((address_space(1))) unsigned int*)(g),
      (__attribute__((address_space(3))) unsigned int*)(l), 16, 0, 0);
}

// ---------------- fp32 -> bf16 convert (all 3 inputs, one launch) ----------------
__global__ void cvt3_kernel(const float* __restrict__ a, int na4,
                            const float* __restrict__ b, int nb4,
                            const float* __restrict__ c, int nc4,
                            unsigned short* __restrict__ oa,
                            unsigned short* __restrict__ ob,
                            unsigned short* __restrict__ oc) {
  int total = na4 + nb4 + nc4;
  for (int i = blockIdx.x * blockDim.x + threadIdx.x; i < total; i += gridDim.x * blockDim.x) {
    const float* src; unsigned short* dst; int j = i;
    if (j < na4) { src = a; dst = oa; }
    else if (j - na4 < nb4) { j -= na4; src = b; dst = ob; }
    else { j -= na4 + nb4; src = c; dst = oc; }
    float4 v = reinterpret_cast<const float4*>(src)[j];
    ushort4 o4;
    o4.x = f32_bf16(v.x); o4.y = f32_bf16(v.y);
    o4.z = f32_bf16(v.z); o4.w = f32_bf16(v.w);
    reinterpret_cast<ushort4*>(dst)[j] = o4;
  }
}

// ---------------- QKV GEMM: 256x256 8-phase (T3+T4+T5), BK=64 ----------------
__global__ __launch_bounds__(512, 2) void gemm_qkv_8ph(const unsigned short* __restrict__ A,
                                                       const unsigned short* __restrict__ Bm,
                                                       unsigned short* __restrict__ qkv) {
  extern __shared__ unsigned short SM[];  // 65536 elems = 131072 B
  const int tid  = threadIdx.x;
  const int lane = tid & 63;
  const int w    = tid >> 6;          // 0..7
  const int wr   = w >> 2, wc = w & 3;
  const int l16  = lane & 15, lh = lane >> 4;
  const int sw   = l16 & 7;
  const int m0   = blockIdx.y * 256;
  const int n0   = blockIdx.x * 256;

  f32x4 acc[8][4];
#pragma unroll
  for (int mi = 0; mi < 8; ++mi)
#pragma unroll
    for (int ni = 0; ni < 4; ++ni) acc[mi][ni] = 0.f;

  const int r0 = tid >> 3,         h0 = (tid & 7) ^ (r0 & 7);
  const int r1 = (tid + 512) >> 3, h1 = (tid & 7) ^ (r1 & 7);
  const unsigned short* Asrc[2][2];
  const unsigned short* Bsrc[2][2];
  Asrc[0][0] = A + (size_t)(m0 + r0) * 1024 + h0 * 8;
  Asrc[0][1] = A + (size_t)(m0 + r1) * 1024 + h1 * 8;
  Asrc[1][0] = A + (size_t)(m0 + 128 + r0) * 1024 + h0 * 8;
  Asrc[1][1] = A + (size_t)(m0 + 128 + r1) * 1024 + h1 * 8;
  Bsrc[0][0] = Bm + (size_t)(n0 + r0) * 1024 + h0 * 8;
  Bsrc[0][1] = Bm + (size_t)(n0 + r1) * 1024 + h1 * 8;
  Bsrc[1][0] = Bm + (size_t)(n0 + 128 + r0) * 1024 + h0 * 8;
  Bsrc[1][1] = Bm + (size_t)(n0 + 128 + r1) * 1024 + h1 * 8;
  const int ld0 = (w * 64) * 8;
  const int ld1 = (512 + w * 64) * 8;

#define STAGE_A(buf, h, U) do { \
    gload16(Asrc[h][0] + (U) * 64, SM + (buf) * 32768 + (h) * 8192 + ld0); \
    gload16(Asrc[h][1] + (U) * 64, SM + (buf) * 32768 + (h) * 8192 + ld1); } while (0)
#define STAGE_B(buf, h, U) do { \
    gload16(Bsrc[h][0] + (U) * 64, SM + (buf) * 32768 + 16384 + (h) * 8192 + ld0); \
    gload16(Bsrc[h][1] + (U) * 64, SM + (buf) * 32768 + 16384 + (h) * 8192 + ld1); } while (0)

  STAGE_A(0, 0, 0); STAGE_A(0, 1, 0);
  STAGE_B(0, 0, 0); STAGE_B(0, 1, 0);
  STAGE_B(1, 0, 1); STAGE_B(1, 1, 1);
  asm volatile("s_waitcnt vmcnt(4)" ::: "memory");
  __builtin_amdgcn_s_barrier();

  const int NT = 16;  // K/64
#pragma unroll 2
  for (int U = 0; U < NT; ++U) {
    const int b = U & 1;
    const unsigned short* Ab = SM + b * 32768 + wr * 8192;
    const unsigned short* Bb = SM + b * 32768 + 16384 + (wc >> 1) * 8192;
    const int rB = (wc & 1) * 64;
    bf16x8 bfr[4][2], af[2][2];

#define LDA(i, j) (*(const bf16x8*)(Ab + (((i) * 16 + l16) * 8 + (((j) * 4 + lh) ^ sw)) * 8))
#define LDB(n, j) (*(const bf16x8*)(Bb + (((rB + (n) * 16 + l16)) * 8 + (((j) * 4 + lh) ^ sw)) * 8))
#define PHASE_MFMA(p) \
    __builtin_amdgcn_s_setprio(1); \
    _Pragma("unroll") \
    for (int n = 0; n < 4; ++n) { \
      acc[2*(p)][n]   = MFMA16(af[0][0], bfr[n][0], acc[2*(p)][n]); \
      acc[2*(p)][n]   = MFMA16(af[0][1], bfr[n][1], acc[2*(p)][n]); \
      acc[2*(p)+1][n] = MFMA16(af[1][0], bfr[n][0], acc[2*(p)+1][n]); \
      acc[2*(p)+1][n] = MFMA16(af[1][1], bfr[n][1], acc[2*(p)+1][n]); \
    } \
    __builtin_amdgcn_s_setprio(0);

    af[0][0] = LDA(0, 0); af[0][1] = LDA(0, 1);
    af[1][0] = LDA(1, 0); af[1][1] = LDA(1, 1);
#pragma unroll
    for (int n = 0; n < 4; ++n) { bfr[n][0] = LDB(n, 0); bfr[n][1] = LDB(n, 1); }
    if (U + 1 < NT) STAGE_A(b ^ 1, 0, U + 1);
    __builtin_amdgcn_s_barrier();
    PHASE_MFMA(0)
    __builtin_amdgcn_s_barrier();
    af[0][0] = LDA(2, 0); af[0][1] = LDA(2, 1);
    af[1][0] = LDA(3, 0); af[1][1] = LDA(3, 1);
    if (U + 1 < NT) STAGE_A(b ^ 1, 1, U + 1);
    __builtin_amdgcn_s_barrier();
    PHASE_MFMA(1)
    __builtin_amdgcn_s_barrier();
    af[0][0] = LDA(4, 0); af[0][1] = LDA(4, 1);
    af[1][0] = LDA(5, 0); af[1][1] = LDA(5, 1);
    if (U + 2 < NT) STAGE_B(b, 0, U + 2);
    __builtin_amdgcn_s_barrier();
    PHASE_MFMA(2)
    __builtin_amdgcn_s_barrier();
    af[0][0] = LDA(6, 0); af[0][1] = LDA(6, 1);
    af[1][0] = LDA(7, 0); af[1][1] = LDA(7, 1);
    if (U + 2 < NT) STAGE_B(b, 1, U + 2);
    __builtin_amdgcn_s_barrier();
    PHASE_MFMA(3)
    asm volatile("s_waitcnt vmcnt(4)" ::: "memory");
    __builtin_amdgcn_s_barrier();
#undef LDA
#undef LDB
#undef PHASE_MFMA
  }

  __syncthreads();
  unsigned short* Ep = SM + w * 8192;
  const int gn0 = n0 + wc * 64;
  const int cc  = gn0 >> 10;
  const int hh2 = (gn0 & 1023) >> 6;
  const int gm0 = m0 + wr * 128;
  const int bb2 = gm0 >> 11;
  const int ss0 = gm0 & 2047;
  const int bh2 = bb2 * 16 + hh2;

  if (cc < 2) {
    const float qsc = (cc == 0) ? 0.18033688f : 1.0f;  // 1/sqrt(64)*log2(e)
#pragma unroll
    for (int mi = 0; mi < 8; ++mi)
#pragma unroll
      for (int ni = 0; ni < 4; ++ni)
#pragma unroll
        for (int r = 0; r < 4; ++r) {
          int row = mi * 16 + lh * 4 + r;
          int col = (ni * 16 + l16) ^ (lh << 3);
          Ep[row * 64 + col] = f32_bf16(acc[mi][ni][r] * qsc);
        }
    unsigned short* qk = qkv + (((size_t)cc * 32 + bh2) * 2048 + ss0) * 64;
#pragma unroll
    for (int it = 0; it < 16; ++it) {
      int ci = it * 64 + lane;
      int row = ci >> 3, c = ci & 7;
      short8 vv = *(const short8*)(Ep + row * 64 + ((c ^ ((row >> 2) & 3)) * 8));
      *(short8*)(qk + (size_t)row * 64 + c * 8) = vv;
    }
  } else {
#pragma unroll
    for (int mi = 0; mi < 8; ++mi)
#pragma unroll
      for (int ni = 0; ni < 4; ++ni) {
        int dk = ni * 16 + l16;
        int ssl = mi * 16 + lh * 4;
        unsigned lo, hi;
        asm("v_cvt_pk_bf16_f32 %0, %1, %2" : "=v"(lo) : "v"(acc[mi][ni][0]), "v"(acc[mi][ni][1]));
        asm("v_cvt_pk_bf16_f32 %0, %1, %2" : "=v"(hi) : "v"(acc[mi][ni][2]), "v"(acc[mi][ni][3]));
        int off = dk * 128 + (ssl ^ ((dk & 7) << 3));
        *(uint2*)(Ep + off) = make_uint2(lo, hi);
      }
    unsigned short* vt = qkv + (size_t)8388608 + (size_t)bh2 * 64 * 2048 + ss0;
#pragma unroll
    for (int it = 0; it < 16; ++it) {
      int ci = it * 64 + lane;
      int dk = ci >> 4, c = ci & 15;
      short8 vv = *(const short8*)(Ep + dk * 128 + ((c ^ (dk & 7)) * 8));
      *(short8*)(vt + (size_t)dk * 2048 + c * 8) = vv;
    }
  }
#undef STAGE_A
#undef STAGE_B
}

// ------- out-proj GEMM, C = A * B^T, BM=64 x BN=128 (2 blocks/CU co-resident) -----
__global__ __launch_bounds__(256) void gemm_out(const unsigned short* __restrict__ A,
                                                const unsigned short* __restrict__ Bm,
                                                float* __restrict__ C,
                                                int M, int N, int K) {
  extern __shared__ unsigned short SM[];  // 32768 B
  unsigned short* As = SM;                // 2048 elems (64 x 32)
  unsigned short* Bs = SM + 2048;         // 4096 elems (128 x 32)
  const int tid  = threadIdx.x;
  const int lane = tid & 63;
  const int wid  = tid >> 6;              // 0..3 (each wave: 64 rows x 32 cols)
  const int l16  = lane & 15, lh = lane >> 4;
  const int m0   = blockIdx.y * 64;
  const int n0   = blockIdx.x * 128;

  f32x4 acc[4][2];
#pragma unroll
  for (int mi = 0; mi < 4; ++mi)
#pragma unroll
    for (int ni = 0; ni < 2; ++ni) acc[mi][ni] = 0.f;

  const unsigned short* aSrc = A + (size_t)(m0 + (tid >> 2)) * K + (tid & 3) * 8;
  const unsigned short* b0   = Bm + (size_t)(n0 + (tid >> 2)) * K + (tid & 3) * 8;
  const unsigned short* b1   = Bm + (size_t)(n0 + 64 + (tid >> 2)) * K + (tid & 3) * 8;
  const int dA  = wid * 512;
  const int dB0 = wid * 512;
  const int dB1 = 2048 + wid * 512;

  for (int k0 = 0; k0 < K; k0 += 32) {
    __syncthreads();
    gload16(aSrc + k0, As + dA);
    gload16(b0 + k0, Bs + dB0);
    gload16(b1 + k0, Bs + dB1);
    __syncthreads();
    bf16x8 af[4], bfr[2];
#pragma unroll
    for (int mi = 0; mi < 4; ++mi)
      af[mi] = *(const bf16x8*)(As + (mi * 16 + l16) * 32 + lh * 8);
#pragma unroll
    for (int ni = 0; ni < 2; ++ni)
      bfr[ni] = *(const bf16x8*)(Bs + (wid * 32 + ni * 16 + l16) * 32 + lh * 8);
#pragma unroll
    for (int mi = 0; mi < 4; ++mi)
#pragma unroll
      for (int ni = 0; ni < 2; ++ni)
        acc[mi][ni] = MFMA16(af[mi], bfr[ni], acc[mi][ni]);
  }

  __syncthreads();
  float* Ef = (float*)SM + wid * 2048;    // per-wave 8KB [64][32] f32, col XOR
#pragma unroll
  for (int mi = 0; mi < 4; ++mi)
#pragma unroll
    for (int ni = 0; ni < 2; ++ni)
#pragma unroll
      for (int r = 0; r < 4; ++r) {
        int row = mi * 16 + lh * 4 + r;
        int col = (ni * 16 + l16) ^ ((row & 7) << 2);
        Ef[row * 32 + col] = acc[mi][ni][r];
      }
  // wave-private region: lgkm ordering within wave, no barrier needed
#pragma unroll
  for (int it = 0; it < 8; ++it) {
    int ci = it * 64 + lane;
    int row = ci >> 3, c4 = ci & 7;
    float4 vv = *(const float4*)(Ef + row * 32 + ((c4 * 4) ^ ((row & 7) << 2)));
    *(float4*)(&C[(size_t)(m0 + row) * N + n0 + wid * 32 + c4 * 4]) = vv;
  }
}

// ---- static LPT job table: 48 jobs per head, descending length ----
__device__ const signed char JQT[48] = {31,31,30,15, 30,29,29,28,14, 28,27,27,26,13, 26,25,25,24,12,
                                        24,23,23,22,11, 22,21,21,20,10, 20,19,19,18, 9, 18,17,17,16, 8,
                                        16, 7, 6, 5, 4, 3, 2, 1, 0};
__device__ const signed char JS0[48] = { 0,16, 0, 0, 16, 0,15, 0, 0, 15, 0,14, 0, 0, 14, 0,13, 0, 0,
                                        13, 0,12, 0, 0, 12, 0,11, 0, 0, 11, 0,10, 0, 0, 10, 0, 9, 0, 0,
                                         9, 0, 0, 0, 0, 0, 0, 0, 0};
__device__ const signed char JNT[48] = {16,16,16,16, 15,15,15,15,15, 14,14,14,14,14, 13,13,13,13,13,
                                        12,12,12,12,12, 11,11,11,11,11, 10,10,10,10,10,  9, 9, 9, 9, 9,
                                         8, 8, 7, 6, 5, 4, 3, 2, 1};
__device__ const signed char JSL[48] = {30,31,28,-1, 29,26,27,24,-1, 25,22,23,20,-1, 21,18,19,16,-1,
                                        17,14,15,12,-1, 13,10,11, 8,-1,  9, 6, 7, 4,-1,  5, 2, 3, 0,-1,
                                         1,-1,-1,-1,-1,-1,-1,-1,-1};

// -------- causal flash attention: 4 waves = 2q-halves x 2kv-halves, 32x32 MFMA,
// in-register P (cvt_pk + permlane32_swap), MFMA row-sums, split-KV LPT jobs.
__global__ __launch_bounds__(256) void attn_kernel(const unsigned short* __restrict__ Qg,
                                                   const unsigned short* __restrict__ Kg,
                                                   const unsigned short* __restrict__ Vtg,
                                                   unsigned short* __restrict__ Og,
                                                   char* __restrict__ parts) {
  __shared__ unsigned short Ks[2][64 * 64];
  __shared__ unsigned short Vs[2][64 * 64];

  const int tid  = threadIdx.x;
  const int lane = tid & 63;
  const int w    = tid >> 6;          // 0..3
  const int wq   = w & 1, wkv = w >> 1;
  const int l31  = lane & 31, hi = lane >> 5;
  const int rx0  = (l31 ^ (l31 >> 3)) & 7;

  const int jb   = blockIdx.x >> 5;   // job 0..47 (desc length)
  const int bh   = blockIdx.x & 31;
  const int qt   = JQT[jb];
  const int ts0  = JS0[jb];
  const int tend = ts0 + JNT[jb];
  const int slot = JSL[jb];
  const int bb   = bh >> 4, hh = bh & 15;
  const int qb   = qt * 64;
  const int qcol = qb + wq * 32 + l31;

  const unsigned short* Qh = Qg + (size_t)bh * (2048 * 64);
  const unsigned short* Kh = Kg + (size_t)bh * (2048 * 64);
  const unsigned short* Vh = Vtg + (size_t)bh * (64 * 2048);

  bf16x8 qf[4];
#pragma unroll
  for (int ks = 0; ks < 4; ++ks)
    qf[ks] = *(const bf16x8*)(Qh + (size_t)qcol * 64 + ks * 16 + hi * 8);

  union { short8 s; bf16x8 b; } oneu;
#pragma unroll
  for (int j = 0; j < 8; ++j) oneu.s[j] = 0x3F80;  // bf16 1.0
  const bf16x8 onesf = oneu.b;

  f32x16 o0 = 0.f, o1 = 0.f;   // O^T rows d (0..31 / 32..63), col q
  f32x16 o_l = 0.f;            // MFMA row-sums: element 0 tracks l (all rows equal)
  float mreg = 0.f;            // defer-max baseline 0 (exp2-space)

  const int sA = tid, sB = tid + 256;
  const int rA = sA >> 3, hA = (sA & 7) ^ ((rA ^ (rA >> 3)) & 7);
  const int rB = sB >> 3, hB = (sB & 7) ^ ((rB ^ (rB >> 3)) & 7);
  const unsigned short* kSrcA = Kh + rA * 64 + hA * 8;
  const unsigned short* kSrcB = Kh + rB * 64 + hB * 8;
  const unsigned short* vSrcA = Vh + (size_t)rA * 2048 + hA * 8;
  const unsigned short* vSrcB = Vh + (size_t)rB * 2048 + hB * 8;
  const int ldsA = (w * 64) * 8;
  const int ldsB = (256 + w * 64) * 8;

  gload16(kSrcA + (size_t)(ts0 * 64) * 64, &Ks[0][ldsA]);
  gload16(kSrcB + (size_t)(ts0 * 64) * 64, &Ks[0][ldsB]);
  gload16(vSrcA + ts0 * 64, &Vs[0][ldsA]);
  gload16(vSrcB + ts0 * 64, &Vs[0][ldsB]);
  __syncthreads();

  const unsigned short* kA = kSrcA + (size_t)(ts0 + 1) * 4096;
  const unsigned short* kB = kSrcB + (size_t)(ts0 + 1) * 4096;
  const unsigned short* vA = vSrcA + (ts0 + 1) * 64;
  const unsigned short* vB = vSrcB + (ts0 + 1) * 64;

  for (int t = ts0; t < tend; ++t) {
    const int kv0 = t * 64;
    const int cur = (t - ts0) & 1;
    if (t + 1 < tend) {
      gload16(kA, &Ks[cur ^ 1][ldsA]);
      gload16(kB, &Ks[cur ^ 1][ldsB]);
      gload16(vA, &Vs[cur ^ 1][ldsA]);
      gload16(vB, &Vs[cur ^ 1][ldsB]);
      kA += 4096; kB += 4096; vA += 64; vB += 64;
    }
    const unsigned short* Kb = Ks[cur];
    const unsigned short* Vb = Vs[cur];

    // S^T = K(kv-half) x Q^T
    f32x16 s = 0.f;
    const int kvl = wkv * 32 + l31;
#pragma unroll
    for (int ks = 0; ks < 4; ++ks) {
      int c = (ks * 2 + hi) ^ rx0 ^ (wkv << 2);
      bf16x8 ka = *(const bf16x8*)(Kb + kvl * 64 + c * 8);
      s = MFMA32(ka, qf[ks], s);
    }

    if (t == qt) {  // causal mask (diag tile; fully-masked wave -> p=0, inert)
#pragma unroll
      for (int r = 0; r < 16; ++r) {
        int kvp = kv0 + wkv * 32 + (r & 3) + 8 * (r >> 2) + 4 * hi;
        if (kvp > qcol) s[r] = -__builtin_inff();
      }
    }

    // defer-max fast path: v_max3 tree, no shuffles, no rescale
    float pm = fmaxf(fmaxf(s[0], s[1]), s[2]);
    pm = fmaxf(fmaxf(pm, s[3]), s[4]);
    pm = fmaxf(fmaxf(pm, s[5]), s[6]);
    pm = fmaxf(fmaxf(pm, s[7]), s[8]);
    pm = fmaxf(fmaxf(pm, s[9]), s[10]);
    pm = fmaxf(fmaxf(pm, s[11]), s[12]);
    pm = fmaxf(fmaxf(pm, s[13]), s[14]);
    pm = fmaxf(pm, s[15]);
    if (!__all(pm <= mreg + 8.f)) {
      float t0 = fmaxf(pm, __shfl_xor(pm, 32));
      float mn = fmaxf(mreg, t0);
      float esc = fast_exp2(mreg - mn);
      mreg = mn;
      o_l[0] *= esc;   // only element 0 of o_l is ever read
#pragma unroll
      for (int r = 0; r < 16; ++r) { o0[r] *= esc; o1[r] *= esc; }
    }

    // P = exp2(s - m); in-register pack to PV B-fragments
    float p[16];
#pragma unroll
    for (int r = 0; r < 16; ++r) p[r] = fast_exp2(s[r] - mreg);

    bf16x8 pf[2];
#pragma unroll
    for (int ks = 0; ks < 2; ++ks) {
      const int off = ks * 8;
      unsigned a1, b1, a2, b2;
      asm("v_cvt_pk_bf16_f32 %0, %1, %2" : "=v"(a1) : "v"(p[off + 0]), "v"(p[off + 1]));
      asm("v_cvt_pk_bf16_f32 %0, %1, %2" : "=v"(b1) : "v"(p[off + 4]), "v"(p[off + 5]));
      asm("v_cvt_pk_bf16_f32 %0, %1, %2" : "=v"(a2) : "v"(p[off + 2]), "v"(p[off + 3]));
      asm("v_cvt_pk_bf16_f32 %0, %1, %2" : "=v"(b2) : "v"(p[off + 6]), "v"(p[off + 7]));
      asm("v_permlane32_swap_b32 %0, %1" : "+v"(a1), "+v"(b1));
      asm("v_permlane32_swap_b32 %0, %1" : "+v"(a2), "+v"(b2));
      union { unsigned u[4]; bf16x8 f; } fr;
      fr.u[0] = a1; fr.u[1] = a2; fr.u[2] = b1; fr.u[3] = b2;
      pf[ks] = fr.f;
    }

    // row-sums on the MFMA pipe: every row of o_l = sum_kv P (read elem 0);
    // P here is the bf16-rounded P, identical to what PV consumes (bias cancels).
    o_l = MFMA32(onesf, pf[0], o_l);
    o_l = MFMA32(onesf, pf[1], o_l);

    // O^T += V^T(kv-half) x P^T
#pragma unroll
    for (int ks = 0; ks < 2; ++ks) {
      int cbase = wkv * 4 + ks * 2 + hi;
      bf16x8 va0 = *(const bf16x8*)(Vb + l31 * 64 + (cbase ^ rx0) * 8);
      bf16x8 va1 = *(const bf16x8*)(Vb + (32 + l31) * 64 + (cbase ^ rx0 ^ 4) * 8);
      o0 = MFMA32(va0, pf[ks], o0);
      o1 = MFMA32(va1, pf[ks], o1);
    }
    __syncthreads();
  }

  const float ll = o_l[0];

  // ---- kv-half merge via LDS (exact m/l-weighted), then store ----
  float* oxch = (float*)Ks;          // [2 wq][64 d][32 q] f32 = 16 KB
  float* lmx  = (float*)Vs;          // [wq*64 + q] = l, [wq*64+32+q] = m
  if (wkv == 1) {
    float* dst = oxch + wq * 2048;
#pragma unroll
    for (int r = 0; r < 16; ++r) {
      int d0 = (r & 3) + 8 * (r >> 2) + 4 * hi;
      dst[d0 * 32 + l31] = o0[r];
      dst[(32 + d0) * 32 + l31] = o1[r];
    }
    if (hi == 0) { lmx[wq * 64 + l31] = ll; lmx[wq * 64 + 32 + l31] = mreg; }
  }
  __syncthreads();
  if (wkv == 0) {
    float lB = lmx[wq * 64 + l31];
    float mB = lmx[wq * 64 + 32 + l31];
    float mx = fmaxf(mreg, mB);
    float wA = fast_exp2(mreg - mx), wB = fast_exp2(mB - mx);
    float lT = ll * wA + lB * wB;
    float inv = (slot < 0) ? (1.f / lT) : 1.f;
    float sA2 = wA * inv, sB2 = wB * inv;
    const float* src = oxch + wq * 2048;
    unsigned short* slab = (unsigned short*)((char*)Vs + 1024) + wq * 2048;  // 4KB/wave
#pragma unroll
    for (int i = 0; i < 8; ++i) {
      int r = 2 * i;
      int d0 = (r & 3) + 8 * (r >> 2) + 4 * hi;
      float x0 = o0[r] * sA2 + src[d0 * 32 + l31] * sB2;
      float x1 = o0[r + 1] * sA2 + src[(d0 + 1) * 32 + l31] * sB2;
      float y0 = o1[r] * sA2 + src[(32 + d0) * 32 + l31] * sB2;
      float y1 = o1[r + 1] * sA2 + src[(33 + d0) * 32 + l31] * sB2;
      unsigned u0, u1;
      asm("v_cvt_pk_bf16_f32 %0, %1, %2" : "=v"(u0) : "v"(x0), "v"(x1));
      asm("v_cvt_pk_bf16_f32 %0, %1, %2" : "=v"(u1) : "v"(y0), "v"(y1));
      *(unsigned*)(slab + l31 * 64 + (((d0 >> 3) ^ (l31 & 7)) * 8) + (d0 & 7)) = u0;
      int d1 = 32 + d0;
      *(unsigned*)(slab + l31 * 64 + (((d1 >> 3) ^ (l31 & 7)) * 8) + (d1 & 7)) = u1;
    }
    if (slot < 0) {
      unsigned short* op = Og + (size_t)bb * 2048 * 1024 + (size_t)hh * 64;
#pragma unroll
      for (int it = 0; it < 4; ++it) {
        int ci = it * 64 + lane;
        int qr = ci >> 3, c = ci & 7;
        short8 vv = *(const short8*)(slab + qr * 64 + ((c ^ (qr & 7)) * 8));
        *(short8*)(op + (size_t)(qb + wq * 32 + qr) * 1024 + c * 8) = vv;
      }
    } else {
      char* pb = parts + (size_t)(bh * 32 + slot) * 8704;
      float* pl = (float*)pb;
      float* pmv = pl + 64;
      unsigned short* pO = (unsigned short*)(pb + 512);
      if (hi == 0) { pl[wq * 32 + l31] = lT; pmv[wq * 32 + l31] = mx; }
#pragma unroll
      for (int it = 0; it < 4; ++it) {
        int ci = it * 64 + lane;
        int qr = ci >> 3, c = ci & 7;
        short8 vv = *(const short8*)(slab + qr * 64 + ((c ^ (qr & 7)) * 8));
        *(short8*)(pO + (size_t)(wq * 32 + qr) * 64 + c * 8) = vv;
      }
    }
  }
}

// -------- merge: combine two KV-half partials per (bh, qt>=16) into att --------
__global__ __launch_bounds__(256) void merge_kernel(const char* __restrict__ parts,
                                                    unsigned short* __restrict__ Og) {
  const int task = blockIdx.x;        // 0..511
  const int bh = task & 31, qi = task >> 5;
  const int qt = 16 + qi;
  const int bb = bh >> 4, hh = bh & 15;
  const int tid = threadIdx.x;
  const int r = tid >> 2, q = tid & 3;

  const char* pb1 = parts + (size_t)(bh * 32 + 2 * qi) * 8704;
  const char* pb2 = parts + (size_t)(bh * 32 + 2 * qi + 1) * 8704;
  const float* l1p = (const float*)pb1;
  const float* l2p = (const float*)pb2;
  float lv1 = l1p[r], mv1 = l1p[64 + r];
  float lv2 = l2p[r], mv2 = l2p[64 + r];
  float mx = fmaxf(mv1, mv2);
  float w1 = fast_exp2(mv1 - mx), w2 = fast_exp2(mv2 - mx);
  float inv = 1.f / (lv1 * w1 + lv2 * w2);
  float s1 = w1 * inv, s2 = w2 * inv;

  const unsigned short* O1 = (const unsigned short*)(pb1 + 512) + r * 64 + q * 16;
  const unsigned short* O2 = (const unsigned short*)(pb2 + 512) + r * 64 + q * 16;
  short8 a0 = *(const short8*)(O1);
  short8 a1 = *(const short8*)(O1 + 8);
  short8 b0 = *(const short8*)(O2);
  short8 b1 = *(const short8*)(O2 + 8);

  unsigned outw[8];
#pragma unroll
  for (int i = 0; i < 4; ++i) {
    float x0 = __builtin_bit_cast(float, ((unsigned)(unsigned short)a0[2 * i]) << 16) * s1 +
               __builtin_bit_cast(float, ((unsigned)(unsigned short)b0[2 * i]) << 16) * s2;
    float x1 = __builtin_bit_cast(float, ((unsigned)(unsigned short)a0[2 * i + 1]) << 16) * s1 +
               __builtin_bit_cast(float, ((unsigned)(unsigned short)b0[2 * i + 1]) << 16) * s2;
    asm("v_cvt_pk_bf16_f32 %0, %1, %2" : "=v"(outw[i]) : "v"(x0), "v"(x1));
    float y0 = __builtin_bit_cast(float, ((unsigned)(unsigned short)a1[2 * i]) << 16) * s1 +
               __builtin_bit_cast(float, ((unsigned)(unsigned short)b1[2 * i]) << 16) * s2;
    float y1 = __builtin_bit_cast(float, ((unsigned)(unsigned short)a1[2 * i + 1]) << 16) * s1 +
               __builtin_bit_cast(float, ((unsigned)(unsigned short)b1[2 * i + 1]) << 16) * s2;
    asm("v_cvt_pk_bf16_f32 %0, %1, %2" : "=v"(outw[4 + i]) : "v"(y0), "v"(y1));
  }
  unsigned short* op = Og + ((size_t)bb * 2048 + qt * 64 + r) * 1024 + hh * 64 + q * 16;
  *(uint4*)(op)     = make_uint4(outw[0], outw[1], outw[2], outw[3]);
  *(uint4*)(op + 8) = make_uint4(outw[4], outw[5], outw[6], outw[7]);
}

extern "C" void kernel_launch(void* const* d_in, const int* in_sizes, int n_in,
                              void* d_out, int out_size, void* d_ws, size_t ws_size,
                              hipStream_t stream) {
  const float* x    = (const float*)d_in[0];
  const float* Wqkv = (const float*)d_in[1];
  const float* Wout = (const float*)d_in[2];
  float* out = (float*)d_out;

  char* ws = (char*)d_ws;
  unsigned short* xb  = (unsigned short*)(ws);                              // [0,8M)
  unsigned short* wqb = (unsigned short*)(ws + (size_t)8 * 1024 * 1024);    // [8M,14M)
  unsigned short* wob = (unsigned short*)(ws + (size_t)14 * 1024 * 1024);   // [14M,16M)
  unsigned short* qkv = (unsigned short*)(ws + (size_t)16 * 1024 * 1024);   // [16M,40M)
  unsigned short* att = (unsigned short*)(ws + (size_t)40 * 1024 * 1024);   // [40M,48M)
  char* parts = ws;   // partials (8.9MB) overlay xb+wqb — dead after qkv gemm

  static bool attr_set = false;
  if (!attr_set) {
    hipFuncSetAttribute((const void*)gemm_qkv_8ph,
                        hipFuncAttributeMaxDynamicSharedMemorySize, 131072);
    attr_set = true;
  }

  cvt3_kernel<<<2048, 256, 0, stream>>>(x, 4194304 / 4, Wqkv, 3145728 / 4,
                                        Wout, 1048576 / 4, xb, wqb, wob);

  // QKV projection (8-phase 256^2) -> Q,K [bh][s][dk] (Q exp2-scaled); V^T [bh][dk][s]
  gemm_qkv_8ph<<<dim3(12, 16), 512, 131072, stream>>>(xb, wqb, qkv);

  const unsigned short* Qp  = qkv;
  const unsigned short* Kp  = qkv + 4194304;
  const unsigned short* Vtp = qkv + 8388608;
  attn_kernel<<<1536, 256, 0, stream>>>(Qp, Kp, Vtp, att, parts);
  merge_kernel<<<512, 256, 0, stream>>>(parts, att);

  // output projection -> fp32 out (BM=64 x BN=128, grid 512 = 2 blocks/CU)
  gemm_out<<<dim3(8, 64), 256, 32768, stream>>>(att, wob, out, 4096, 1024, 1024);
}

// Round 15
// 106.568 us; speedup vs baseline: 1.0620x; 1.0620x over previous
//
#include <hip/hip_runtime.h>
#include <hip/hip_bf16.h>
#include <stdint.h>

typedef __attribute__((ext_vector_type(8)))  __bf16 bf16x8;
typedef __attribute__((ext_vector_type(8)))  short  short8;
typedef __attribute__((ext_vector_type(4)))  float  f32x4;
typedef __attribute__((ext_vector_type(16))) float  f32x16;

#define MFMA16(a, b, c) __builtin_amdgcn_mfma_f32_16x16x32_bf16((a), (b), (c), 0, 0, 0)
#define MFMA32(a, b, c) __builtin_amdgcn_mfma_f32_32x32x16_bf16((a), (b), (c), 0, 0, 0)

__device__ __forceinline__ unsigned short f32_bf16(float f) {
  union { float f; unsigned u; } v; v.f = f;
  unsigned r = v.u + 0x7FFFu + ((v.u >> 16) & 1u);
  return (unsigned short)(r >> 16);
}

// bare v_exp_f32 (2^x): OCML exp2f carries denormal guards (~5 insts)
__device__ __forceinline__ float fast_exp2(float x) {
#if __has_builtin(__builtin_amdgcn_exp2f)
  return __builtin_amdgcn_exp2f(x);
#else
  return __expf(x * 0.69314718f);
#endif
}

// async global->LDS, 16B per lane; LDS dest is wave-uniform base (+lane*16 by HW)
__device__ __forceinline__ void gload16(const unsigned short* g, unsigned short* l) {
  __builtin_amdgcn_global_load_lds(
      (const __attribute__((address_space(1))) unsigned int*)(g),
      (__attribute__((address_space(3))) unsigned int*)(l), 16, 0, 0);
}

// ---------------- fp32 -> bf16 convert (all 3 inputs, one launch) ----------------
__global__ void cvt3_kernel(const float* __restrict__ a, int na4,
                            const float* __restrict__ b, int nb4,
                            const float* __restrict__ c, int nc4,
                            unsigned short* __restrict__ oa,
                            unsigned short* __restrict__ ob,
                            unsigned short* __restrict__ oc) {
  int total = na4 + nb4 + nc4;
  for (int i = blockIdx.x * blockDim.x + threadIdx.x; i < total; i += gridDim.x * blockDim.x) {
    const float* src; unsigned short* dst; int j = i;
    if (j < na4) { src = a; dst = oa; }
    else if (j - na4 < nb4) { j -= na4; src = b; dst = ob; }
    else { j -= na4 + nb4; src = c; dst = oc; }
    float4 v = reinterpret_cast<const float4*>(src)[j];
    ushort4 o4;
    o4.x = f32_bf16(v.x); o4.y = f32_bf16(v.y);
    o4.z = f32_bf16(v.z); o4.w = f32_bf16(v.w);
    reinterpret_cast<ushort4*>(dst)[j] = o4;
  }
}

// ---------------- QKV GEMM: 256x256 8-phase (T3+T4+T5), BK=64 ----------------
__global__ __launch_bounds__(512, 2) void gemm_qkv_8ph(const unsigned short* __restrict__ A,
                                                       const unsigned short* __restrict__ Bm,
                                                       unsigned short* __restrict__ qkv) {
  extern __shared__ unsigned short SM[];  // 65536 elems = 131072 B
  const int tid  = threadIdx.x;
  const int lane = tid & 63;
  const int w    = tid >> 6;          // 0..7
  const int wr   = w >> 2, wc = w & 3;
  const int l16  = lane & 15, lh = lane >> 4;
  const int sw   = l16 & 7;
  const int m0   = blockIdx.y * 256;
  const int n0   = blockIdx.x * 256;

  f32x4 acc[8][4];
#pragma unroll
  for (int mi = 0; mi < 8; ++mi)
#pragma unroll
    for (int ni = 0; ni < 4; ++ni) acc[mi][ni] = 0.f;

  const int r0 = tid >> 3,         h0 = (tid & 7) ^ (r0 & 7);
  const int r1 = (tid + 512) >> 3, h1 = (tid & 7) ^ (r1 & 7);
  const unsigned short* Asrc[2][2];
  const unsigned short* Bsrc[2][2];
  Asrc[0][0] = A + (size_t)(m0 + r0) * 1024 + h0 * 8;
  Asrc[0][1] = A + (size_t)(m0 + r1) * 1024 + h1 * 8;
  Asrc[1][0] = A + (size_t)(m0 + 128 + r0) * 1024 + h0 * 8;
  Asrc[1][1] = A + (size_t)(m0 + 128 + r1) * 1024 + h1 * 8;
  Bsrc[0][0] = Bm + (size_t)(n0 + r0) * 1024 + h0 * 8;
  Bsrc[0][1] = Bm + (size_t)(n0 + r1) * 1024 + h1 * 8;
  Bsrc[1][0] = Bm + (size_t)(n0 + 128 + r0) * 1024 + h0 * 8;
  Bsrc[1][1] = Bm + (size_t)(n0 + 128 + r1) * 1024 + h1 * 8;
  const int ld0 = (w * 64) * 8;
  const int ld1 = (512 + w * 64) * 8;

#define STAGE_A(buf, h, U) do { \
    gload16(Asrc[h][0] + (U) * 64, SM + (buf) * 32768 + (h) * 8192 + ld0); \
    gload16(Asrc[h][1] + (U) * 64, SM + (buf) * 32768 + (h) * 8192 + ld1); } while (0)
#define STAGE_B(buf, h, U) do { \
    gload16(Bsrc[h][0] + (U) * 64, SM + (buf) * 32768 + 16384 + (h) * 8192 + ld0); \
    gload16(Bsrc[h][1] + (U) * 64, SM + (buf) * 32768 + 16384 + (h) * 8192 + ld1); } while (0)

  STAGE_A(0, 0, 0); STAGE_A(0, 1, 0);
  STAGE_B(0, 0, 0); STAGE_B(0, 1, 0);
  STAGE_B(1, 0, 1); STAGE_B(1, 1, 1);
  asm volatile("s_waitcnt vmcnt(4)" ::: "memory");
  __builtin_amdgcn_s_barrier();

  const int NT = 16;  // K/64
#pragma unroll 2
  for (int U = 0; U < NT; ++U) {
    const int b = U & 1;
    const unsigned short* Ab = SM + b * 32768 + wr * 8192;
    const unsigned short* Bb = SM + b * 32768 + 16384 + (wc >> 1) * 8192;
    const int rB = (wc & 1) * 64;
    bf16x8 bfr[4][2], af[2][2];

#define LDA(i, j) (*(const bf16x8*)(Ab + (((i) * 16 + l16) * 8 + (((j) * 4 + lh) ^ sw)) * 8))
#define LDB(n, j) (*(const bf16x8*)(Bb + (((rB + (n) * 16 + l16)) * 8 + (((j) * 4 + lh) ^ sw)) * 8))
#define PHASE_MFMA(p) \
    __builtin_amdgcn_s_setprio(1); \
    _Pragma("unroll") \
    for (int n = 0; n < 4; ++n) { \
      acc[2*(p)][n]   = MFMA16(af[0][0], bfr[n][0], acc[2*(p)][n]); \
      acc[2*(p)][n]   = MFMA16(af[0][1], bfr[n][1], acc[2*(p)][n]); \
      acc[2*(p)+1][n] = MFMA16(af[1][0], bfr[n][0], acc[2*(p)+1][n]); \
      acc[2*(p)+1][n] = MFMA16(af[1][1], bfr[n][1], acc[2*(p)+1][n]); \
    } \
    __builtin_amdgcn_s_setprio(0);

    af[0][0] = LDA(0, 0); af[0][1] = LDA(0, 1);
    af[1][0] = LDA(1, 0); af[1][1] = LDA(1, 1);
#pragma unroll
    for (int n = 0; n < 4; ++n) { bfr[n][0] = LDB(n, 0); bfr[n][1] = LDB(n, 1); }
    if (U + 1 < NT) STAGE_A(b ^ 1, 0, U + 1);
    __builtin_amdgcn_s_barrier();
    PHASE_MFMA(0)
    __builtin_amdgcn_s_barrier();
    af[0][0] = LDA(2, 0); af[0][1] = LDA(2, 1);
    af[1][0] = LDA(3, 0); af[1][1] = LDA(3, 1);
    if (U + 1 < NT) STAGE_A(b ^ 1, 1, U + 1);
    __builtin_amdgcn_s_barrier();
    PHASE_MFMA(1)
    __builtin_amdgcn_s_barrier();
    af[0][0] = LDA(4, 0); af[0][1] = LDA(4, 1);
    af[1][0] = LDA(5, 0); af[1][1] = LDA(5, 1);
    if (U + 2 < NT) STAGE_B(b, 0, U + 2);
    __builtin_amdgcn_s_barrier();
    PHASE_MFMA(2)
    __builtin_amdgcn_s_barrier();
    af[0][0] = LDA(6, 0); af[0][1] = LDA(6, 1);
    af[1][0] = LDA(7, 0); af[1][1] = LDA(7, 1);
    if (U + 2 < NT) STAGE_B(b, 1, U + 2);
    __builtin_amdgcn_s_barrier();
    PHASE_MFMA(3)
    asm volatile("s_waitcnt vmcnt(4)" ::: "memory");
    __builtin_amdgcn_s_barrier();
#undef LDA
#undef LDB
#undef PHASE_MFMA
  }

  __syncthreads();
  unsigned short* Ep = SM + w * 8192;
  const int gn0 = n0 + wc * 64;
  const int cc  = gn0 >> 10;
  const int hh2 = (gn0 & 1023) >> 6;
  const int gm0 = m0 + wr * 128;
  const int bb2 = gm0 >> 11;
  const int ss0 = gm0 & 2047;
  const int bh2 = bb2 * 16 + hh2;

  if (cc < 2) {
    const float qsc = (cc == 0) ? 0.18033688f : 1.0f;  // 1/sqrt(64)*log2(e)
#pragma unroll
    for (int mi = 0; mi < 8; ++mi)
#pragma unroll
      for (int ni = 0; ni < 4; ++ni)
#pragma unroll
        for (int r = 0; r < 4; ++r) {
          int row = mi * 16 + lh * 4 + r;
          int col = (ni * 16 + l16) ^ (lh << 3);
          Ep[row * 64 + col] = f32_bf16(acc[mi][ni][r] * qsc);
        }
    unsigned short* qk = qkv + (((size_t)cc * 32 + bh2) * 2048 + ss0) * 64;
#pragma unroll
    for (int it = 0; it < 16; ++it) {
      int ci = it * 64 + lane;
      int row = ci >> 3, c = ci & 7;
      short8 vv = *(const short8*)(Ep + row * 64 + ((c ^ ((row >> 2) & 3)) * 8));
      *(short8*)(qk + (size_t)row * 64 + c * 8) = vv;
    }
  } else {
#pragma unroll
    for (int mi = 0; mi < 8; ++mi)
#pragma unroll
      for (int ni = 0; ni < 4; ++ni) {
        int dk = ni * 16 + l16;
        int ssl = mi * 16 + lh * 4;
        unsigned lo, hi;
        asm("v_cvt_pk_bf16_f32 %0, %1, %2" : "=v"(lo) : "v"(acc[mi][ni][0]), "v"(acc[mi][ni][1]));
        asm("v_cvt_pk_bf16_f32 %0, %1, %2" : "=v"(hi) : "v"(acc[mi][ni][2]), "v"(acc[mi][ni][3]));
        int off = dk * 128 + (ssl ^ ((dk & 7) << 3));
        *(uint2*)(Ep + off) = make_uint2(lo, hi);
      }
    unsigned short* vt = qkv + (size_t)8388608 + (size_t)bh2 * 64 * 2048 + ss0;
#pragma unroll
    for (int it = 0; it < 16; ++it) {
      int ci = it * 64 + lane;
      int dk = ci >> 4, c = ci & 15;
      short8 vv = *(const short8*)(Ep + dk * 128 + ((c ^ (dk & 7)) * 8));
      *(short8*)(vt + (size_t)dk * 2048 + c * 8) = vv;
    }
  }
#undef STAGE_A
#undef STAGE_B
}

// ------- out-proj GEMM, C = A * B^T, BM=64 x BN=128 (2 blocks/CU co-resident) -----
__global__ __launch_bounds__(256) void gemm_out(const unsigned short* __restrict__ A,
                                                const unsigned short* __restrict__ Bm,
                                                float* __restrict__ C,
                                                int M, int N, int K) {
  extern __shared__ unsigned short SM[];  // 32768 B
  unsigned short* As = SM;                // 2048 elems (64 x 32)
  unsigned short* Bs = SM + 2048;         // 4096 elems (128 x 32)
  const int tid  = threadIdx.x;
  const int lane = tid & 63;
  const int wid  = tid >> 6;              // 0..3 (each wave: 64 rows x 32 cols)
  const int l16  = lane & 15, lh = lane >> 4;
  const int m0   = blockIdx.y * 64;
  const int n0   = blockIdx.x * 128;

  f32x4 acc[4][2];
#pragma unroll
  for (int mi = 0; mi < 4; ++mi)
#pragma unroll
    for (int ni = 0; ni < 2; ++ni) acc[mi][ni] = 0.f;

  const unsigned short* aSrc = A + (size_t)(m0 + (tid >> 2)) * K + (tid & 3) * 8;
  const unsigned short* b0   = Bm + (size_t)(n0 + (tid >> 2)) * K + (tid & 3) * 8;
  const unsigned short* b1   = Bm + (size_t)(n0 + 64 + (tid >> 2)) * K + (tid & 3) * 8;
  const int dA  = wid * 512;
  const int dB0 = wid * 512;
  const int dB1 = 2048 + wid * 512;

  for (int k0 = 0; k0 < K; k0 += 32) {
    __syncthreads();
    gload16(aSrc + k0, As + dA);
    gload16(b0 + k0, Bs + dB0);
    gload16(b1 + k0, Bs + dB1);
    __syncthreads();
    bf16x8 af[4], bfr[2];
#pragma unroll
    for (int mi = 0; mi < 4; ++mi)
      af[mi] = *(const bf16x8*)(As + (mi * 16 + l16) * 32 + lh * 8);
#pragma unroll
    for (int ni = 0; ni < 2; ++ni)
      bfr[ni] = *(const bf16x8*)(Bs + (wid * 32 + ni * 16 + l16) * 32 + lh * 8);
#pragma unroll
    for (int mi = 0; mi < 4; ++mi)
#pragma unroll
      for (int ni = 0; ni < 2; ++ni)
        acc[mi][ni] = MFMA16(af[mi], bfr[ni], acc[mi][ni]);
  }

  __syncthreads();
  float* Ef = (float*)SM + wid * 2048;    // per-wave 8KB [64][32] f32, col XOR
#pragma unroll
  for (int mi = 0; mi < 4; ++mi)
#pragma unroll
    for (int ni = 0; ni < 2; ++ni)
#pragma unroll
      for (int r = 0; r < 4; ++r) {
        int row = mi * 16 + lh * 4 + r;
        int col = (ni * 16 + l16) ^ ((row & 7) << 2);
        Ef[row * 32 + col] = acc[mi][ni][r];
      }
  // wave-private region: lgkm ordering within wave, no barrier needed
#pragma unroll
  for (int it = 0; it < 8; ++it) {
    int ci = it * 64 + lane;
    int row = ci >> 3, c4 = ci & 7;
    float4 vv = *(const float4*)(Ef + row * 32 + ((c4 * 4) ^ ((row & 7) << 2)));
    *(float4*)(&C[(size_t)(m0 + row) * N + n0 + wid * 32 + c4 * 4]) = vv;
  }
}

// ---- static LPT job table: 48 jobs per head, descending length ----
__device__ const signed char JQT[48] = {31,31,30,15, 30,29,29,28,14, 28,27,27,26,13, 26,25,25,24,12,
                                        24,23,23,22,11, 22,21,21,20,10, 20,19,19,18, 9, 18,17,17,16, 8,
                                        16, 7, 6, 5, 4, 3, 2, 1, 0};
__device__ const signed char JS0[48] = { 0,16, 0, 0, 16, 0,15, 0, 0, 15, 0,14, 0, 0, 14, 0,13, 0, 0,
                                        13, 0,12, 0, 0, 12, 0,11, 0, 0, 11, 0,10, 0, 0, 10, 0, 9, 0, 0,
                                         9, 0, 0, 0, 0, 0, 0, 0, 0};
__device__ const signed char JNT[48] = {16,16,16,16, 15,15,15,15,15, 14,14,14,14,14, 13,13,13,13,13,
                                        12,12,12,12,12, 11,11,11,11,11, 10,10,10,10,10,  9, 9, 9, 9, 9,
                                         8, 8, 7, 6, 5, 4, 3, 2, 1};
__device__ const signed char JSL[48] = {30,31,28,-1, 29,26,27,24,-1, 25,22,23,20,-1, 21,18,19,16,-1,
                                        17,14,15,12,-1, 13,10,11, 8,-1,  9, 6, 7, 4,-1,  5, 2, 3, 0,-1,
                                         1,-1,-1,-1,-1,-1,-1,-1,-1};

// -------- causal flash attention: 4 waves = 2q-halves x 2kv-halves, 32x32 MFMA,
// in-register P (cvt_pk + permlane32_swap), split-KV static LPT jobs + partials.
__global__ __launch_bounds__(256) void attn_kernel(const unsigned short* __restrict__ Qg,
                                                   const unsigned short* __restrict__ Kg,
                                                   const unsigned short* __restrict__ Vtg,
                                                   unsigned short* __restrict__ Og,
                                                   char* __restrict__ parts) {
  __shared__ unsigned short Ks[2][64 * 64];
  __shared__ unsigned short Vs[2][64 * 64];

  const int tid  = threadIdx.x;
  const int lane = tid & 63;
  const int w    = tid >> 6;          // 0..3
  const int wq   = w & 1, wkv = w >> 1;
  const int l31  = lane & 31, hi = lane >> 5;
  const int rx0  = (l31 ^ (l31 >> 3)) & 7;

  const int jb   = blockIdx.x >> 5;   // job 0..47 (desc length)
  const int bh   = blockIdx.x & 31;
  const int qt   = JQT[jb];
  const int ts0  = JS0[jb];
  const int tend = ts0 + JNT[jb];
  const int slot = JSL[jb];
  const int bb   = bh >> 4, hh = bh & 15;
  const int qb   = qt * 64;
  const int qcol = qb + wq * 32 + l31;

  const unsigned short* Qh = Qg + (size_t)bh * (2048 * 64);
  const unsigned short* Kh = Kg + (size_t)bh * (2048 * 64);
  const unsigned short* Vh = Vtg + (size_t)bh * (64 * 2048);

  bf16x8 qf[4];
#pragma unroll
  for (int ks = 0; ks < 4; ++ks)
    qf[ks] = *(const bf16x8*)(Qh + (size_t)qcol * 64 + ks * 16 + hi * 8);

  f32x16 o0 = 0.f, o1 = 0.f;   // O^T rows d (0..31 / 32..63), col q
  float mreg = 0.f, ll = 0.f;  // defer-max baseline 0 (exp2-space)

  const int sA = tid, sB = tid + 256;
  const int rA = sA >> 3, hA = (sA & 7) ^ ((rA ^ (rA >> 3)) & 7);
  const int rB = sB >> 3, hB = (sB & 7) ^ ((rB ^ (rB >> 3)) & 7);
  const unsigned short* kSrcA = Kh + rA * 64 + hA * 8;
  const unsigned short* kSrcB = Kh + rB * 64 + hB * 8;
  const unsigned short* vSrcA = Vh + (size_t)rA * 2048 + hA * 8;
  const unsigned short* vSrcB = Vh + (size_t)rB * 2048 + hB * 8;
  const int ldsA = (w * 64) * 8;
  const int ldsB = (256 + w * 64) * 8;

  gload16(kSrcA + (size_t)(ts0 * 64) * 64, &Ks[0][ldsA]);
  gload16(kSrcB + (size_t)(ts0 * 64) * 64, &Ks[0][ldsB]);
  gload16(vSrcA + ts0 * 64, &Vs[0][ldsA]);
  gload16(vSrcB + ts0 * 64, &Vs[0][ldsB]);
  __syncthreads();

  // pointer-bumped prefetch addresses (next tile)
  const unsigned short* kA = kSrcA + (size_t)(ts0 + 1) * 4096;
  const unsigned short* kB = kSrcB + (size_t)(ts0 + 1) * 4096;
  const unsigned short* vA = vSrcA + (ts0 + 1) * 64;
  const unsigned short* vB = vSrcB + (ts0 + 1) * 64;

  for (int t = ts0; t < tend; ++t) {
    const int kv0 = t * 64;
    const int cur = (t - ts0) & 1;
    if (t + 1 < tend) {
      gload16(kA, &Ks[cur ^ 1][ldsA]);
      gload16(kB, &Ks[cur ^ 1][ldsB]);
      gload16(vA, &Vs[cur ^ 1][ldsA]);
      gload16(vB, &Vs[cur ^ 1][ldsB]);
      kA += 4096; kB += 4096; vA += 64; vB += 64;
    }
    const unsigned short* Kb = Ks[cur];
    const unsigned short* Vb = Vs[cur];

    // S^T = K(kv-half) x Q^T: rows kv_local, col q. 4 dk slices.
    f32x16 s = 0.f;
    const int kvl = wkv * 32 + l31;
#pragma unroll
    for (int ks = 0; ks < 4; ++ks) {
      int c = (ks * 2 + hi) ^ rx0 ^ (wkv << 2);
      bf16x8 ka = *(const bf16x8*)(Kb + kvl * 64 + c * 8);
      s = MFMA32(ka, qf[ks], s);
    }

    if (t == qt) {  // causal mask (diag tile; fully-masked wave -> all p=0, inert)
#pragma unroll
      for (int r = 0; r < 16; ++r) {
        int kvp = kv0 + wkv * 32 + (r & 3) + 8 * (r >> 2) + 4 * hi;
        if (kvp > qcol) s[r] = -__builtin_inff();
      }
    }

    // defer-max fast path: v_max3 tree, no shuffles, no rescale
    float pm = fmaxf(fmaxf(s[0], s[1]), s[2]);
    pm = fmaxf(fmaxf(pm, s[3]), s[4]);
    pm = fmaxf(fmaxf(pm, s[5]), s[6]);
    pm = fmaxf(fmaxf(pm, s[7]), s[8]);
    pm = fmaxf(fmaxf(pm, s[9]), s[10]);
    pm = fmaxf(fmaxf(pm, s[11]), s[12]);
    pm = fmaxf(fmaxf(pm, s[13]), s[14]);
    pm = fmaxf(pm, s[15]);
    if (!__all(pm <= mreg + 8.f)) {
      float t0 = fmaxf(pm, __shfl_xor(pm, 32));
      float mn = fmaxf(mreg, t0);
      float esc = fast_exp2(mreg - mn);
      mreg = mn; ll *= esc;
#pragma unroll
      for (int r = 0; r < 16; ++r) { o0[r] *= esc; o1[r] *= esc; }
    }

    // P = exp2(s - m); lane-local sums; in-register pack to PV B-fragments
    float p[16];
#pragma unroll
    for (int r = 0; r < 16; ++r) p[r] = fast_exp2(s[r] - mreg);
    float ps = ((p[0] + p[1]) + (p[2] + p[3])) + ((p[4] + p[5]) + (p[6] + p[7]))
             + ((p[8] + p[9]) + (p[10] + p[11])) + ((p[12] + p[13]) + (p[14] + p[15]));
    ps += __shfl_xor(ps, 32);
    ll += ps;

    bf16x8 pf[2];
#pragma unroll
    for (int ks = 0; ks < 2; ++ks) {
      const int off = ks * 8;
      unsigned a1, b1, a2, b2;
      asm("v_cvt_pk_bf16_f32 %0, %1, %2" : "=v"(a1) : "v"(p[off + 0]), "v"(p[off + 1]));
      asm("v_cvt_pk_bf16_f32 %0, %1, %2" : "=v"(b1) : "v"(p[off + 4]), "v"(p[off + 5]));
      asm("v_cvt_pk_bf16_f32 %0, %1, %2" : "=v"(a2) : "v"(p[off + 2]), "v"(p[off + 3]));
      asm("v_cvt_pk_bf16_f32 %0, %1, %2" : "=v"(b2) : "v"(p[off + 6]), "v"(p[off + 7]));
      asm("v_permlane32_swap_b32 %0, %1" : "+v"(a1), "+v"(b1));
      asm("v_permlane32_swap_b32 %0, %1" : "+v"(a2), "+v"(b2));
      union { unsigned u[4]; bf16x8 f; } fr;
      fr.u[0] = a1; fr.u[1] = a2; fr.u[2] = b1; fr.u[3] = b2;
      pf[ks] = fr.f;
    }

    // O^T += V^T(kv-half) x P^T
#pragma unroll
    for (int ks = 0; ks < 2; ++ks) {
      int cbase = wkv * 4 + ks * 2 + hi;
      bf16x8 va0 = *(const bf16x8*)(Vb + l31 * 64 + (cbase ^ rx0) * 8);
      bf16x8 va1 = *(const bf16x8*)(Vb + (32 + l31) * 64 + (cbase ^ rx0 ^ 4) * 8);
      o0 = MFMA32(va0, pf[ks], o0);
      o1 = MFMA32(va1, pf[ks], o1);
    }
    __syncthreads();
  }

  // ---- kv-half merge via LDS (exact m/l-weighted), then store ----
  float* oxch = (float*)Ks;          // [2 wq][64 d][32 q] f32 = 16 KB
  float* lmx  = (float*)Vs;          // [wq*64 + q] = l, [wq*64+32+q] = m
  if (wkv == 1) {
    float* dst = oxch + wq * 2048;
#pragma unroll
    for (int r = 0; r < 16; ++r) {
      int d0 = (r & 3) + 8 * (r >> 2) + 4 * hi;
      dst[d0 * 32 + l31] = o0[r];
      dst[(32 + d0) * 32 + l31] = o1[r];
    }
    if (hi == 0) { lmx[wq * 64 + l31] = ll; lmx[wq * 64 + 32 + l31] = mreg; }
  }
  __syncthreads();
  if (wkv == 0) {
    float lB = lmx[wq * 64 + l31];
    float mB = lmx[wq * 64 + 32 + l31];
    float mx = fmaxf(mreg, mB);
    float wA = fast_exp2(mreg - mx), wB = fast_exp2(mB - mx);
    float lT = ll * wA + lB * wB;
    float inv = (slot < 0) ? (1.f / lT) : 1.f;
    float sA2 = wA * inv, sB2 = wB * inv;
    const float* src = oxch + wq * 2048;
    unsigned short* slab = (unsigned short*)((char*)Vs + 1024) + wq * 2048;  // 4KB/wave
#pragma unroll
    for (int i = 0; i < 8; ++i) {
      int r = 2 * i;
      int d0 = (r & 3) + 8 * (r >> 2) + 4 * hi;
      float x0 = o0[r] * sA2 + src[d0 * 32 + l31] * sB2;
      float x1 = o0[r + 1] * sA2 + src[(d0 + 1) * 32 + l31] * sB2;
      float y0 = o1[r] * sA2 + src[(32 + d0) * 32 + l31] * sB2;
      float y1 = o1[r + 1] * sA2 + src[(33 + d0) * 32 + l31] * sB2;
      unsigned u0, u1;
      asm("v_cvt_pk_bf16_f32 %0, %1, %2" : "=v"(u0) : "v"(x0), "v"(x1));
      asm("v_cvt_pk_bf16_f32 %0, %1, %2" : "=v"(u1) : "v"(y0), "v"(y1));
      *(unsigned*)(slab + l31 * 64 + (((d0 >> 3) ^ (l31 & 7)) * 8) + (d0 & 7)) = u0;
      int d1 = 32 + d0;
      *(unsigned*)(slab + l31 * 64 + (((d1 >> 3) ^ (l31 & 7)) * 8) + (d1 & 7)) = u1;
    }
    if (slot < 0) {
      unsigned short* op = Og + (size_t)bb * 2048 * 1024 + (size_t)hh * 64;
#pragma unroll
      for (int it = 0; it < 4; ++it) {
        int ci = it * 64 + lane;
        int qr = ci >> 3, c = ci & 7;
        short8 vv = *(const short8*)(slab + qr * 64 + ((c ^ (qr & 7)) * 8));
        *(short8*)(op + (size_t)(qb + wq * 32 + qr) * 1024 + c * 8) = vv;
      }
    } else {
      char* pb = parts + (size_t)(bh * 32 + slot) * 8704;
      float* pl = (float*)pb;
      float* pmv = pl + 64;
      unsigned short* pO = (unsigned short*)(pb + 512);
      if (hi == 0) { pl[wq * 32 + l31] = lT; pmv[wq * 32 + l31] = mx; }
#pragma unroll
      for (int it = 0; it < 4; ++it) {
        int ci = it * 64 + lane;
        int qr = ci >> 3, c = ci & 7;
        short8 vv = *(const short8*)(slab + qr * 64 + ((c ^ (qr & 7)) * 8));
        *(short8*)(pO + (size_t)(wq * 32 + qr) * 64 + c * 8) = vv;
      }
    }
  }
}

// -------- merge: combine two KV-half partials per (bh, qt>=16) into att --------
__global__ __launch_bounds__(256) void merge_kernel(const char* __restrict__ parts,
                                                    unsigned short* __restrict__ Og) {
  const int task = blockIdx.x;        // 0..511
  const int bh = task & 31, qi = task >> 5;
  const int qt = 16 + qi;
  const int bb = bh >> 4, hh = bh & 15;
  const int tid = threadIdx.x;
  const int r = tid >> 2, q = tid & 3;

  const char* pb1 = parts + (size_t)(bh * 32 + 2 * qi) * 8704;
  const char* pb2 = parts + (size_t)(bh * 32 + 2 * qi + 1) * 8704;
  const float* l1p = (const float*)pb1;
  const float* l2p = (const float*)pb2;
  float lv1 = l1p[r], mv1 = l1p[64 + r];
  float lv2 = l2p[r], mv2 = l2p[64 + r];
  float mx = fmaxf(mv1, mv2);
  float w1 = fast_exp2(mv1 - mx), w2 = fast_exp2(mv2 - mx);
  float inv = 1.f / (lv1 * w1 + lv2 * w2);
  float s1 = w1 * inv, s2 = w2 * inv;

  const unsigned short* O1 = (const unsigned short*)(pb1 + 512) + r * 64 + q * 16;
  const unsigned short* O2 = (const unsigned short*)(pb2 + 512) + r * 64 + q * 16;
  short8 a0 = *(const short8*)(O1);
  short8 a1 = *(const short8*)(O1 + 8);
  short8 b0 = *(const short8*)(O2);
  short8 b1 = *(const short8*)(O2 + 8);

  unsigned outw[8];
#pragma unroll
  for (int i = 0; i < 4; ++i) {
    float x0 = __builtin_bit_cast(float, ((unsigned)(unsigned short)a0[2 * i]) << 16) * s1 +
               __builtin_bit_cast(float, ((unsigned)(unsigned short)b0[2 * i]) << 16) * s2;
    float x1 = __builtin_bit_cast(float, ((unsigned)(unsigned short)a0[2 * i + 1]) << 16) * s1 +
               __builtin_bit_cast(float, ((unsigned)(unsigned short)b0[2 * i + 1]) << 16) * s2;
    asm("v_cvt_pk_bf16_f32 %0, %1, %2" : "=v"(outw[i]) : "v"(x0), "v"(x1));
    float y0 = __builtin_bit_cast(float, ((unsigned)(unsigned short)a1[2 * i]) << 16) * s1 +
               __builtin_bit_cast(float, ((unsigned)(unsigned short)b1[2 * i]) << 16) * s2;
    float y1 = __builtin_bit_cast(float, ((unsigned)(unsigned short)a1[2 * i + 1]) << 16) * s1 +
               __builtin_bit_cast(float, ((unsigned)(unsigned short)b1[2 * i + 1]) << 16) * s2;
    asm("v_cvt_pk_bf16_f32 %0, %1, %2" : "=v"(outw[4 + i]) : "v"(y0), "v"(y1));
  }
  unsigned short* op = Og + ((size_t)bb * 2048 + qt * 64 + r) * 1024 + hh * 64 + q * 16;
  *(uint4*)(op)     = make_uint4(outw[0], outw[1], outw[2], outw[3]);
  *(uint4*)(op + 8) = make_uint4(outw[4], outw[5], outw[6], outw[7]);
}

extern "C" void kernel_launch(void* const* d_in, const int* in_sizes, int n_in,
                              void* d_out, int out_size, void* d_ws, size_t ws_size,
                              hipStream_t stream) {
  const float* x    = (const float*)d_in[0];
  const float* Wqkv = (const float*)d_in[1];
  const float* Wout = (const float*)d_in[2];
  float* out = (float*)d_out;

  char* ws = (char*)d_ws;
  unsigned short* xb  = (unsigned short*)(ws);                              // [0,8M)
  unsigned short* wqb = (unsigned short*)(ws + (size_t)8 * 1024 * 1024);    // [8M,14M)
  unsigned short* wob = (unsigned short*)(ws + (size_t)14 * 1024 * 1024);   // [14M,16M)
  unsigned short* qkv = (unsigned short*)(ws + (size_t)16 * 1024 * 1024);   // [16M,40M)
  unsigned short* att = (unsigned short*)(ws + (size_t)40 * 1024 * 1024);   // [40M,48M)
  char* parts = ws;   // partials (8.9MB) overlay xb+wqb — dead after qkv gemm

  static bool attr_set = false;
  if (!attr_set) {
    hipFuncSetAttribute((const void*)gemm_qkv_8ph,
                        hipFuncAttributeMaxDynamicSharedMemorySize, 131072);
    attr_set = true;
  }

  cvt3_kernel<<<2048, 256, 0, stream>>>(x, 4194304 / 4, Wqkv, 3145728 / 4,
                                        Wout, 1048576 / 4, xb, wqb, wob);

  // QKV projection (8-phase 256^2) -> Q,K [bh][s][dk] (Q exp2-scaled); V^T [bh][dk][s]
  gemm_qkv_8ph<<<dim3(12, 16), 512, 131072, stream>>>(xb, wqb, qkv);

  const unsigned short* Qp  = qkv;
  const unsigned short* Kp  = qkv + 4194304;
  const unsigned short* Vtp = qkv + 8388608;
  attn_kernel<<<1536, 256, 0, stream>>>(Qp, Kp, Vtp, att, parts);
  merge_kernel<<<512, 256, 0, stream>>>(parts, att);

  // output projection -> fp32 out (BM=64 x BN=128, grid 512 = 2 blocks/CU)
  gemm_out<<<dim3(8, 64), 256, 32768, stream>>>(att, wob, out, 4096, 1024, 1024);
}